// Round 7
// baseline (809.638 us; speedup 1.0000x reference)
//
#include <hip/hip_runtime.h>
#include <math.h>

// ---------------------------------------------------------------------------
// FraudDetectionGCN: 3x GCNConv(relu) + FC + log_softmax, fp32 throughout.
// R7 changes vs R6:
//  * lin kernels: LDS-staged tiles. R6's nt broadcast loads refetched each
//    64B line ~4x (FETCH 63MB for a 26MB input) and nt stores evicted g from
//    LLC. Now: stage TR rows of h into LDS with fully-coalesced float4 loads
//    (1KB useful/wave-instr), compute with same-address ds_read_b128
//    (broadcast, conflict-free) x L1-resident W reads. Plain cached ops.
// norm factorization: out[n] = dinv[n]*(sum_{s->n} g[s] + g[n]) + b,
// where g = dinv[:,None] * (h @ W).
// ---------------------------------------------------------------------------

static inline size_t alignup(size_t x){ return (x + 511) & ~size_t(511); }

typedef float v4f __attribute__((ext_vector_type(4)));

#define NBUCK 1024          // histogram bins (dst>>7), NB=ceil(N/128) used
#define CHUNK 8192          // edges per block in hist/scatter
#define CCAP  3584          // max edges per bucket (mean ~2046, +30 sigma)

__global__ void zero_kernel(int* __restrict__ p, int n){
  int i = blockIdx.x*256 + threadIdx.x;
  if(i<n) p[i] = 0;
}

// Pass A: global histogram of dst>>7 (LDS-aggregated).
__global__ __launch_bounds__(256) void hist_kernel(const int* __restrict__ dst,
                                                   int* __restrict__ bcnt, int E){
  __shared__ int h[NBUCK];
  int t = threadIdx.x;
  for(int i=t;i<NBUCK;i+=256) h[i]=0;
  __syncthreads();
  int base = blockIdx.x*CHUNK;
  #pragma unroll 4
  for(int i=0;i<CHUNK;i+=256){
    int e = base+i+t;
    if(e<E) atomicAdd(&h[dst[e]>>7], 1);
  }
  __syncthreads();
  for(int i=t;i<NBUCK;i+=256) if(h[i]) atomicAdd(&bcnt[i], h[i]);
}

// Exclusive scan of 1024 bucket counts (single block). bbase = bfill = prefix.
__global__ void scan_buckets_kernel(const int* __restrict__ bcnt, int* __restrict__ bbase,
                                    int* __restrict__ bfill){
  __shared__ int sh[256];
  int t = threadIdx.x;
  int v0=bcnt[4*t], v1=bcnt[4*t+1], v2=bcnt[4*t+2], v3=bcnt[4*t+3];
  int ts = v0+v1+v2+v3;
  sh[t]=ts; __syncthreads();
  for(int off=1; off<256; off<<=1){
    int x=(t>=off)?sh[t-off]:0; __syncthreads();
    sh[t]+=x; __syncthreads();
  }
  int run = sh[t]-ts;
  int i0=4*t;
  bbase[i0+0]=run; bfill[i0+0]=run; run+=v0;
  bbase[i0+1]=run; bfill[i0+1]=run; run+=v1;
  bbase[i0+2]=run; bfill[i0+2]=run; run+=v2;
  bbase[i0+3]=run; bfill[i0+3]=run;
}

// Pass B: scatter packed (local_dst<<17 | src) into bucket regions.
__global__ __launch_bounds__(256) void scatter_kernel(const int* __restrict__ src,
                                                      const int* __restrict__ dst,
                                                      int* __restrict__ bfill,
                                                      int* __restrict__ pairs, int E){
  __shared__ int h[NBUCK];
  __shared__ int base[NBUCK];
  int t = threadIdx.x;
  for(int i=t;i<NBUCK;i+=256) h[i]=0;
  __syncthreads();
  int cbase = blockIdx.x*CHUNK;
  int d[CHUNK/256];
  #pragma unroll
  for(int i=0;i<CHUNK/256;i++){
    int e = cbase+i*256+t;
    d[i] = (e<E) ? dst[e] : -1;
    if(d[i]>=0) atomicAdd(&h[d[i]>>7], 1);
  }
  __syncthreads();
  for(int i=t;i<NBUCK;i+=256) base[i] = h[i] ? atomicAdd(&bfill[i], h[i]) : 0;
  __syncthreads();
  #pragma unroll
  for(int i=0;i<CHUNK/256;i++){
    int e = cbase+i*256+t;
    if(d[i]>=0){
      int b = d[i]>>7;
      int slot = atomicAdd(&base[b], 1);
      pairs[slot] = ((d[i]&127)<<17) | src[e];
    }
  }
}

// Pass C: one block per bucket (128 dst nodes). LDS counting sort ->
// row_ptr, dinv, and fully-sequential col writes.
__global__ __launch_bounds__(256) void bucket_csr_kernel(const int* __restrict__ pairs,
                                                         const int* __restrict__ bbase,
                                                         int* __restrict__ row_ptr,
                                                         float* __restrict__ dinv,
                                                         int* __restrict__ col,
                                                         int N, int E){
  __shared__ int hist[128];
  __shared__ int pref[128];
  __shared__ int fill[128];
  __shared__ int srcs[CCAP];
  int b = blockIdx.x, t = threadIdx.x;
  int s = bbase[b], e = bbase[b+1];
  int cnt = e - s; if(cnt > CCAP) cnt = CCAP;   // unreachable guard
  if(t<128) hist[t]=0;
  __syncthreads();
  int v[CCAP/256];
  #pragma unroll
  for(int i=0;i<CCAP/256;i++){
    int idx = i*256 + t;
    if(idx<cnt){ v[i]=pairs[s+idx]; atomicAdd(&hist[v[i]>>17], 1); }
  }
  __syncthreads();
  if(t<128) pref[t]=hist[t];
  __syncthreads();
  for(int off=1; off<128; off<<=1){
    int x=0;
    if(t<128 && t>=off) x=pref[t-off];
    __syncthreads();
    if(t<128) pref[t]+=x;
    __syncthreads();
  }
  if(t<128){
    int ex = pref[t]-hist[t];                 // exclusive prefix
    fill[t]=ex;
    int node = b*128 + t;
    if(node<N){
      row_ptr[node] = s + ex;
      dinv[node] = rsqrtf((float)(hist[t]+1)); // +1 self loop
    }
  }
  if(b==0 && t==0) row_ptr[N]=E;
  __syncthreads();
  #pragma unroll
  for(int i=0;i<CCAP/256;i++){
    int idx = i*256 + t;
    if(idx<cnt){
      int ld = v[i]>>17;
      int pos = atomicAdd(&fill[ld], 1);
      srcs[pos] = v[i] & 0x1FFFF;
    }
  }
  __syncthreads();
  for(int i=t;i<cnt;i+=256) col[s+i]=srcs[i];
}

// g[n,:] = dinv[n] * (h[n,:K] @ W[K,64]).
// LDS-staged: TR rows staged with coalesced float4 loads, then each of the
// 4 waves computes RW=TR/4 rows. lane = output feature. h from LDS via
// same-address ds_read_b128 (broadcast, conflict-free); W[k*64+lane] is a
// 256B coalesced L1-resident read shared by all 4 waves.
template<int K, int TR>
__global__ __launch_bounds__(256) void lin_kernel(const float* __restrict__ h,
                                                  const float* __restrict__ W,
                                                  const float* __restrict__ dinv,
                                                  float* __restrict__ g, int N){
  constexpr int RW = TR/4;
  __shared__ __align__(16) float hs[TR*K];
  int t = threadIdx.x, wave = t>>6, lane = t&63;
  long rbase = (long)blockIdx.x*TR;
  // ---- stage TR rows into LDS (coalesced) ----
  const v4f* hsrc = (const v4f*)(h + rbase*K);
  if(rbase + TR <= N){
    #pragma unroll
    for(int idx = t; idx < TR*K/4; idx += 256)
      ((v4f*)hs)[idx] = hsrc[idx];
  } else {
    int lim = (int)((N - rbase)*K/4);            // tail block (rare/never)
    for(int idx = t; idx < lim; idx += 256)
      ((v4f*)hs)[idx] = hsrc[idx];
  }
  __syncthreads();
  // ---- compute RW rows per wave ----
  float acc[RW];
  #pragma unroll
  for(int r=0;r<RW;r++) acc[r]=0.f;
  const float* hw = hs + wave*RW*K;
  for(int k=0;k<K;k+=4){
    float w0 = W[(k+0)*64+lane];
    float w1 = W[(k+1)*64+lane];
    float w2 = W[(k+2)*64+lane];
    float w3 = W[(k+3)*64+lane];
    #pragma unroll
    for(int r=0;r<RW;r++){
      v4f hv = *(const v4f*)&hw[r*K+k];
      acc[r] += hv.x*w0 + hv.y*w1 + hv.z*w2 + hv.w*w3;
    }
  }
  long row0 = rbase + wave*RW;
  #pragma unroll
  for(int r=0;r<RW;r++){
    if(row0 + r < N)
      g[(row0+r)*64 + lane] = dinv[row0+r]*acc[r];
  }
}

// h[n,:] = relu(dinv[n]*(g[n,:] + sum_{CSR} g[col,:]) + bias). One wave/node,
// lane == feature; 8-deep unroll for outstanding 256B row gathers.
__global__ __launch_bounds__(256) void agg_kernel(const float* __restrict__ g,
                                                  const int* __restrict__ row_ptr,
                                                  const int* __restrict__ col,
                                                  const float* __restrict__ dinv,
                                                  const float* __restrict__ bias,
                                                  float* __restrict__ h, int N){
  int wave = threadIdx.x>>6, lane = threadIdx.x&63;
  int n = blockIdx.x*4 + wave;
  if(n>=N) return;
  int s = row_ptr[n], e = row_ptr[n+1];
  float acc = g[(size_t)n*64 + lane];          // self loop
  int i = s;
  for(; i+8<=e; i+=8){
    int c0=col[i],c1=col[i+1],c2=col[i+2],c3=col[i+3];
    int c4=col[i+4],c5=col[i+5],c6=col[i+6],c7=col[i+7];
    float x0=g[(size_t)c0*64+lane], x1=g[(size_t)c1*64+lane];
    float x2=g[(size_t)c2*64+lane], x3=g[(size_t)c3*64+lane];
    float x4=g[(size_t)c4*64+lane], x5=g[(size_t)c5*64+lane];
    float x6=g[(size_t)c6*64+lane], x7=g[(size_t)c7*64+lane];
    acc += ((x0+x1)+(x2+x3)) + ((x4+x5)+(x6+x7));
  }
  for(; i<e; ++i) acc += g[(size_t)col[i]*64 + lane];
  float r = dinv[n]*acc + bias[lane];
  h[(size_t)n*64 + lane] = fmaxf(r, 0.0f);
}

// Layer-3 agg with fused FC + log_softmax epilogue: never materializes h3.
__global__ __launch_bounds__(256) void agg_final_kernel(const float* __restrict__ g,
                                                        const int* __restrict__ row_ptr,
                                                        const int* __restrict__ col,
                                                        const float* __restrict__ dinv,
                                                        const float* __restrict__ bias,
                                                        const float* __restrict__ Wfc,
                                                        const float* __restrict__ bfc,
                                                        float* __restrict__ out, int N){
  int wave = threadIdx.x>>6, lane = threadIdx.x&63;
  int n = blockIdx.x*4 + wave;
  if(n>=N) return;
  int s = row_ptr[n], e = row_ptr[n+1];
  float acc = g[(size_t)n*64 + lane];          // self loop
  int i = s;
  for(; i+8<=e; i+=8){
    int c0=col[i],c1=col[i+1],c2=col[i+2],c3=col[i+3];
    int c4=col[i+4],c5=col[i+5],c6=col[i+6],c7=col[i+7];
    float x0=g[(size_t)c0*64+lane], x1=g[(size_t)c1*64+lane];
    float x2=g[(size_t)c2*64+lane], x3=g[(size_t)c3*64+lane];
    float x4=g[(size_t)c4*64+lane], x5=g[(size_t)c5*64+lane];
    float x6=g[(size_t)c6*64+lane], x7=g[(size_t)c7*64+lane];
    acc += ((x0+x1)+(x2+x3)) + ((x4+x5)+(x6+x7));
  }
  for(; i<e; ++i) acc += g[(size_t)col[i]*64 + lane];
  float hv = fmaxf(dinv[n]*acc + bias[lane], 0.0f);   // h3[n][lane]
  float2 w = *(const float2*)&Wfc[lane*2];
  float p0 = hv*w.x, p1 = hv*w.y;
  for(int off=32; off; off>>=1){
    p0 += __shfl_down(p0, off);
    p1 += __shfl_down(p1, off);
  }
  if(lane==0){
    float l0 = p0 + bfc[0], l1 = p1 + bfc[1];
    float m  = fmaxf(l0, l1);
    float lse = m + logf(expf(l0-m) + expf(l1-m));
    out[(size_t)n*2+0] = l0 - lse;
    out[(size_t)n*2+1] = l1 - lse;
  }
}

extern "C" void kernel_launch(void* const* d_in, const int* in_sizes, int n_in,
                              void* d_out, int out_size, void* d_ws, size_t ws_size,
                              hipStream_t stream) {
  (void)n_in; (void)out_size; (void)ws_size;
  const float* x   = (const float*)d_in[0];
  const int*   ei  = (const int*)  d_in[1];
  const float* W1  = (const float*)d_in[2];
  const float* b1  = (const float*)d_in[3];
  const float* W2  = (const float*)d_in[4];
  const float* b2  = (const float*)d_in[5];
  const float* W3  = (const float*)d_in[6];
  const float* b3  = (const float*)d_in[7];
  const float* Wfc = (const float*)d_in[8];
  const float* bfc = (const float*)d_in[9];
  float* out = (float*)d_out;

  const int N = in_sizes[0] / 128;   // 100000
  const int E = in_sizes[1] / 2;     // 1600000
  const int* src = ei;
  const int* dst = ei + E;
  const int NB = (N + 127) / 128;    // 782 buckets

  // ---- workspace carve ----
  char* w = (char*)d_ws;
  int*   bcnt    = (int*)  w; w += alignup((size_t)NBUCK*4);
  int*   bbase   = (int*)  w; w += alignup((size_t)(NBUCK+1)*4);
  int*   bfill   = (int*)  w; w += alignup((size_t)NBUCK*4);
  int*   pairs   = (int*)  w; w += alignup((size_t)E*4);
  int*   row_ptr = (int*)  w; w += alignup((size_t)(N+1)*4);
  float* dinv    = (float*)w; w += alignup((size_t)N*4);
  int*   col     = (int*)  w; w += alignup((size_t)E*4);
  float* bufA    = (float*)w; w += alignup((size_t)N*64*4);
  float* bufB    = (float*)w; w += alignup((size_t)N*64*4);

  const int nblkE    = (E + CHUNK - 1) / CHUNK;   // 196
  const int nblkL128 = (N + 31) / 32;             // TR=32 -> 3125 (exact)
  const int nblkL64  = (N + 39) / 40;             // TR=40 -> 2500 (exact)
  const int nblkAgg  = (N + 3) / 4;

  // ---- CSR build ----
  zero_kernel<<<(NBUCK+255)/256, 256, 0, stream>>>(bcnt, NBUCK);
  hist_kernel<<<nblkE, 256, 0, stream>>>(dst, bcnt, E);
  scan_buckets_kernel<<<1, 256, 0, stream>>>(bcnt, bbase, bfill);
  scatter_kernel<<<nblkE, 256, 0, stream>>>(src, dst, bfill, pairs, E);
  bucket_csr_kernel<<<NB, 256, 0, stream>>>(pairs, bbase, row_ptr, dinv, col, N, E);

  // ---- layer 1: x[N,128] ----
  lin_kernel<128,32><<<nblkL128, 256, 0, stream>>>(x, W1, dinv, bufA, N);
  agg_kernel<<<nblkAgg, 256, 0, stream>>>(bufA, row_ptr, col, dinv, b1, bufB, N);
  // ---- layer 2 ----
  lin_kernel<64,40><<<nblkL64, 256, 0, stream>>>(bufB, W2, dinv, bufA, N);
  agg_kernel<<<nblkAgg, 256, 0, stream>>>(bufA, row_ptr, col, dinv, b2, bufB, N);
  // ---- layer 3 + FC + log_softmax (fused) ----
  lin_kernel<64,40><<<nblkL64, 256, 0, stream>>>(bufB, W3, dinv, bufA, N);
  agg_final_kernel<<<nblkAgg, 256, 0, stream>>>(bufA, row_ptr, col, dinv, b3,
                                                Wfc, bfc, out, N);
}

// Round 8
// 448.860 us; speedup vs baseline: 1.8038x; 1.8038x over previous
//
#include <hip/hip_runtime.h>
#include <math.h>

// ---------------------------------------------------------------------------
// FraudDetectionGCN: 3x GCNConv(relu) + FC + log_softmax, fp32 throughout.
// R8 change vs R7:
//  * lin kernels spilled catastrophically (VGPR=256, 405MB scratch writes):
//    compiler fully unrolled the k-loop and hoisted all ds_reads. Fix:
//    #pragma unroll 2 on the k-loop + RW=8 rows/wave (TR=32) -> ~80 live
//    VGPRs, no spill. LDS staging (coalesced in, broadcast ds_read_b128 out)
//    retained from R7.
// norm factorization: out[n] = dinv[n]*(sum_{s->n} g[s] + g[n]) + b,
// where g = dinv[:,None] * (h @ W).
// ---------------------------------------------------------------------------

static inline size_t alignup(size_t x){ return (x + 511) & ~size_t(511); }

typedef float v4f __attribute__((ext_vector_type(4)));

#define NBUCK 1024          // histogram bins (dst>>7), NB=ceil(N/128) used
#define CHUNK 8192          // edges per block in hist/scatter
#define CCAP  3584          // max edges per bucket (mean ~2046, +30 sigma)

__global__ void zero_kernel(int* __restrict__ p, int n){
  int i = blockIdx.x*256 + threadIdx.x;
  if(i<n) p[i] = 0;
}

// Pass A: global histogram of dst>>7 (LDS-aggregated).
__global__ __launch_bounds__(256) void hist_kernel(const int* __restrict__ dst,
                                                   int* __restrict__ bcnt, int E){
  __shared__ int h[NBUCK];
  int t = threadIdx.x;
  for(int i=t;i<NBUCK;i+=256) h[i]=0;
  __syncthreads();
  int base = blockIdx.x*CHUNK;
  #pragma unroll 4
  for(int i=0;i<CHUNK;i+=256){
    int e = base+i+t;
    if(e<E) atomicAdd(&h[dst[e]>>7], 1);
  }
  __syncthreads();
  for(int i=t;i<NBUCK;i+=256) if(h[i]) atomicAdd(&bcnt[i], h[i]);
}

// Exclusive scan of 1024 bucket counts (single block). bbase = bfill = prefix.
__global__ void scan_buckets_kernel(const int* __restrict__ bcnt, int* __restrict__ bbase,
                                    int* __restrict__ bfill){
  __shared__ int sh[256];
  int t = threadIdx.x;
  int v0=bcnt[4*t], v1=bcnt[4*t+1], v2=bcnt[4*t+2], v3=bcnt[4*t+3];
  int ts = v0+v1+v2+v3;
  sh[t]=ts; __syncthreads();
  for(int off=1; off<256; off<<=1){
    int x=(t>=off)?sh[t-off]:0; __syncthreads();
    sh[t]+=x; __syncthreads();
  }
  int run = sh[t]-ts;
  int i0=4*t;
  bbase[i0+0]=run; bfill[i0+0]=run; run+=v0;
  bbase[i0+1]=run; bfill[i0+1]=run; run+=v1;
  bbase[i0+2]=run; bfill[i0+2]=run; run+=v2;
  bbase[i0+3]=run; bfill[i0+3]=run;
}

// Pass B: scatter packed (local_dst<<17 | src) into bucket regions.
__global__ __launch_bounds__(256) void scatter_kernel(const int* __restrict__ src,
                                                      const int* __restrict__ dst,
                                                      int* __restrict__ bfill,
                                                      int* __restrict__ pairs, int E){
  __shared__ int h[NBUCK];
  __shared__ int base[NBUCK];
  int t = threadIdx.x;
  for(int i=t;i<NBUCK;i+=256) h[i]=0;
  __syncthreads();
  int cbase = blockIdx.x*CHUNK;
  int d[CHUNK/256];
  #pragma unroll
  for(int i=0;i<CHUNK/256;i++){
    int e = cbase+i*256+t;
    d[i] = (e<E) ? dst[e] : -1;
    if(d[i]>=0) atomicAdd(&h[d[i]>>7], 1);
  }
  __syncthreads();
  for(int i=t;i<NBUCK;i+=256) base[i] = h[i] ? atomicAdd(&bfill[i], h[i]) : 0;
  __syncthreads();
  #pragma unroll
  for(int i=0;i<CHUNK/256;i++){
    int e = cbase+i*256+t;
    if(d[i]>=0){
      int b = d[i]>>7;
      int slot = atomicAdd(&base[b], 1);
      pairs[slot] = ((d[i]&127)<<17) | src[e];
    }
  }
}

// Pass C: one block per bucket (128 dst nodes). LDS counting sort ->
// row_ptr, dinv, and fully-sequential col writes.
__global__ __launch_bounds__(256) void bucket_csr_kernel(const int* __restrict__ pairs,
                                                         const int* __restrict__ bbase,
                                                         int* __restrict__ row_ptr,
                                                         float* __restrict__ dinv,
                                                         int* __restrict__ col,
                                                         int N, int E){
  __shared__ int hist[128];
  __shared__ int pref[128];
  __shared__ int fill[128];
  __shared__ int srcs[CCAP];
  int b = blockIdx.x, t = threadIdx.x;
  int s = bbase[b], e = bbase[b+1];
  int cnt = e - s; if(cnt > CCAP) cnt = CCAP;   // unreachable guard
  if(t<128) hist[t]=0;
  __syncthreads();
  int v[CCAP/256];
  #pragma unroll
  for(int i=0;i<CCAP/256;i++){
    int idx = i*256 + t;
    if(idx<cnt){ v[i]=pairs[s+idx]; atomicAdd(&hist[v[i]>>17], 1); }
  }
  __syncthreads();
  if(t<128) pref[t]=hist[t];
  __syncthreads();
  for(int off=1; off<128; off<<=1){
    int x=0;
    if(t<128 && t>=off) x=pref[t-off];
    __syncthreads();
    if(t<128) pref[t]+=x;
    __syncthreads();
  }
  if(t<128){
    int ex = pref[t]-hist[t];                 // exclusive prefix
    fill[t]=ex;
    int node = b*128 + t;
    if(node<N){
      row_ptr[node] = s + ex;
      dinv[node] = rsqrtf((float)(hist[t]+1)); // +1 self loop
    }
  }
  if(b==0 && t==0) row_ptr[N]=E;
  __syncthreads();
  #pragma unroll
  for(int i=0;i<CCAP/256;i++){
    int idx = i*256 + t;
    if(idx<cnt){
      int ld = v[i]>>17;
      int pos = atomicAdd(&fill[ld], 1);
      srcs[pos] = v[i] & 0x1FFFF;
    }
  }
  __syncthreads();
  for(int i=t;i<cnt;i+=256) col[s+i]=srcs[i];
}

// g[n,:] = dinv[n] * (h[n,:K] @ W[K,64]).
// LDS-staged: TR=32 rows staged with coalesced float4 loads; each of the
// 4 waves computes RW=8 rows. lane = output feature. h from LDS via
// same-address ds_read_b128 (broadcast, conflict-free); W[k*64+lane] is a
// 256B coalesced L1-resident read. k-loop capped at unroll 2 to avoid the
// R7 register blow-up (full unroll -> 256 VGPR -> 405MB scratch spill).
template<int K>
__global__ __launch_bounds__(256) void lin_kernel(const float* __restrict__ h,
                                                  const float* __restrict__ W,
                                                  const float* __restrict__ dinv,
                                                  float* __restrict__ g, int N){
  constexpr int TR = 32, RW = 8;
  __shared__ __align__(16) float hs[TR*K];
  int t = threadIdx.x, wave = t>>6, lane = t&63;
  long rbase = (long)blockIdx.x*TR;
  // ---- stage TR rows into LDS (coalesced) ----
  const v4f* hsrc = (const v4f*)(h + rbase*K);
  if(rbase + TR <= N){
    #pragma unroll
    for(int idx = t; idx < TR*K/4; idx += 256)
      ((v4f*)hs)[idx] = hsrc[idx];
  } else {
    int lim = (int)((N - rbase)*K/4);            // tail block
    for(int idx = t; idx < lim; idx += 256)
      ((v4f*)hs)[idx] = hsrc[idx];
  }
  __syncthreads();
  // ---- compute RW rows per wave ----
  float acc[RW];
  #pragma unroll
  for(int r=0;r<RW;r++) acc[r]=0.f;
  const float* hw = hs + wave*RW*K;
  #pragma unroll 2
  for(int k=0;k<K;k+=4){
    float w0 = W[(k+0)*64+lane];
    float w1 = W[(k+1)*64+lane];
    float w2 = W[(k+2)*64+lane];
    float w3 = W[(k+3)*64+lane];
    #pragma unroll
    for(int r=0;r<RW;r++){
      v4f hv = *(const v4f*)&hw[r*K+k];
      acc[r] = fmaf(hv.w, w3, fmaf(hv.z, w2, fmaf(hv.y, w1, fmaf(hv.x, w0, acc[r]))));
    }
  }
  long row0 = rbase + wave*RW;
  #pragma unroll
  for(int r=0;r<RW;r++){
    if(row0 + r < N)
      g[(row0+r)*64 + lane] = dinv[row0+r]*acc[r];
  }
}

// h[n,:] = relu(dinv[n]*(g[n,:] + sum_{CSR} g[col,:]) + bias). One wave/node,
// lane == feature; 8-deep unroll for outstanding 256B row gathers.
__global__ __launch_bounds__(256) void agg_kernel(const float* __restrict__ g,
                                                  const int* __restrict__ row_ptr,
                                                  const int* __restrict__ col,
                                                  const float* __restrict__ dinv,
                                                  const float* __restrict__ bias,
                                                  float* __restrict__ h, int N){
  int wave = threadIdx.x>>6, lane = threadIdx.x&63;
  int n = blockIdx.x*4 + wave;
  if(n>=N) return;
  int s = row_ptr[n], e = row_ptr[n+1];
  float acc = g[(size_t)n*64 + lane];          // self loop
  int i = s;
  for(; i+8<=e; i+=8){
    int c0=col[i],c1=col[i+1],c2=col[i+2],c3=col[i+3];
    int c4=col[i+4],c5=col[i+5],c6=col[i+6],c7=col[i+7];
    float x0=g[(size_t)c0*64+lane], x1=g[(size_t)c1*64+lane];
    float x2=g[(size_t)c2*64+lane], x3=g[(size_t)c3*64+lane];
    float x4=g[(size_t)c4*64+lane], x5=g[(size_t)c5*64+lane];
    float x6=g[(size_t)c6*64+lane], x7=g[(size_t)c7*64+lane];
    acc += ((x0+x1)+(x2+x3)) + ((x4+x5)+(x6+x7));
  }
  for(; i<e; ++i) acc += g[(size_t)col[i]*64 + lane];
  float r = dinv[n]*acc + bias[lane];
  h[(size_t)n*64 + lane] = fmaxf(r, 0.0f);
}

// Layer-3 agg with fused FC + log_softmax epilogue: never materializes h3.
__global__ __launch_bounds__(256) void agg_final_kernel(const float* __restrict__ g,
                                                        const int* __restrict__ row_ptr,
                                                        const int* __restrict__ col,
                                                        const float* __restrict__ dinv,
                                                        const float* __restrict__ bias,
                                                        const float* __restrict__ Wfc,
                                                        const float* __restrict__ bfc,
                                                        float* __restrict__ out, int N){
  int wave = threadIdx.x>>6, lane = threadIdx.x&63;
  int n = blockIdx.x*4 + wave;
  if(n>=N) return;
  int s = row_ptr[n], e = row_ptr[n+1];
  float acc = g[(size_t)n*64 + lane];          // self loop
  int i = s;
  for(; i+8<=e; i+=8){
    int c0=col[i],c1=col[i+1],c2=col[i+2],c3=col[i+3];
    int c4=col[i+4],c5=col[i+5],c6=col[i+6],c7=col[i+7];
    float x0=g[(size_t)c0*64+lane], x1=g[(size_t)c1*64+lane];
    float x2=g[(size_t)c2*64+lane], x3=g[(size_t)c3*64+lane];
    float x4=g[(size_t)c4*64+lane], x5=g[(size_t)c5*64+lane];
    float x6=g[(size_t)c6*64+lane], x7=g[(size_t)c7*64+lane];
    acc += ((x0+x1)+(x2+x3)) + ((x4+x5)+(x6+x7));
  }
  for(; i<e; ++i) acc += g[(size_t)col[i]*64 + lane];
  float hv = fmaxf(dinv[n]*acc + bias[lane], 0.0f);   // h3[n][lane]
  float2 w = *(const float2*)&Wfc[lane*2];
  float p0 = hv*w.x, p1 = hv*w.y;
  for(int off=32; off; off>>=1){
    p0 += __shfl_down(p0, off);
    p1 += __shfl_down(p1, off);
  }
  if(lane==0){
    float l0 = p0 + bfc[0], l1 = p1 + bfc[1];
    float m  = fmaxf(l0, l1);
    float lse = m + logf(expf(l0-m) + expf(l1-m));
    out[(size_t)n*2+0] = l0 - lse;
    out[(size_t)n*2+1] = l1 - lse;
  }
}

extern "C" void kernel_launch(void* const* d_in, const int* in_sizes, int n_in,
                              void* d_out, int out_size, void* d_ws, size_t ws_size,
                              hipStream_t stream) {
  (void)n_in; (void)out_size; (void)ws_size;
  const float* x   = (const float*)d_in[0];
  const int*   ei  = (const int*)  d_in[1];
  const float* W1  = (const float*)d_in[2];
  const float* b1  = (const float*)d_in[3];
  const float* W2  = (const float*)d_in[4];
  const float* b2  = (const float*)d_in[5];
  const float* W3  = (const float*)d_in[6];
  const float* b3  = (const float*)d_in[7];
  const float* Wfc = (const float*)d_in[8];
  const float* bfc = (const float*)d_in[9];
  float* out = (float*)d_out;

  const int N = in_sizes[0] / 128;   // 100000
  const int E = in_sizes[1] / 2;     // 1600000
  const int* src = ei;
  const int* dst = ei + E;
  const int NB = (N + 127) / 128;    // 782 buckets

  // ---- workspace carve ----
  char* w = (char*)d_ws;
  int*   bcnt    = (int*)  w; w += alignup((size_t)NBUCK*4);
  int*   bbase   = (int*)  w; w += alignup((size_t)(NBUCK+1)*4);
  int*   bfill   = (int*)  w; w += alignup((size_t)NBUCK*4);
  int*   pairs   = (int*)  w; w += alignup((size_t)E*4);
  int*   row_ptr = (int*)  w; w += alignup((size_t)(N+1)*4);
  float* dinv    = (float*)w; w += alignup((size_t)N*4);
  int*   col     = (int*)  w; w += alignup((size_t)E*4);
  float* bufA    = (float*)w; w += alignup((size_t)N*64*4);
  float* bufB    = (float*)w; w += alignup((size_t)N*64*4);

  const int nblkE   = (E + CHUNK - 1) / CHUNK;   // 196
  const int nblkLin = (N + 31) / 32;             // TR=32 -> 3125 (exact)
  const int nblkAgg = (N + 3) / 4;

  // ---- CSR build ----
  zero_kernel<<<(NBUCK+255)/256, 256, 0, stream>>>(bcnt, NBUCK);
  hist_kernel<<<nblkE, 256, 0, stream>>>(dst, bcnt, E);
  scan_buckets_kernel<<<1, 256, 0, stream>>>(bcnt, bbase, bfill);
  scatter_kernel<<<nblkE, 256, 0, stream>>>(src, dst, bfill, pairs, E);
  bucket_csr_kernel<<<NB, 256, 0, stream>>>(pairs, bbase, row_ptr, dinv, col, N, E);

  // ---- layer 1: x[N,128] ----
  lin_kernel<128><<<nblkLin, 256, 0, stream>>>(x, W1, dinv, bufA, N);
  agg_kernel<<<nblkAgg, 256, 0, stream>>>(bufA, row_ptr, col, dinv, b1, bufB, N);
  // ---- layer 2 ----
  lin_kernel<64><<<nblkLin, 256, 0, stream>>>(bufB, W2, dinv, bufA, N);
  agg_kernel<<<nblkAgg, 256, 0, stream>>>(bufA, row_ptr, col, dinv, b2, bufB, N);
  // ---- layer 3 + FC + log_softmax (fused) ----
  lin_kernel<64><<<nblkLin, 256, 0, stream>>>(bufB, W3, dinv, bufA, N);
  agg_final_kernel<<<nblkAgg, 256, 0, stream>>>(bufA, row_ptr, col, dinv, b3,
                                                Wfc, bfc, out, N);
}

// Round 9
// 408.576 us; speedup vs baseline: 1.9816x; 1.0986x over previous
//
#include <hip/hip_runtime.h>
#include <math.h>

// ---------------------------------------------------------------------------
// FraudDetectionGCN: 3x GCNConv(relu) + FC + log_softmax, fp32 throughout.
// R9 change vs R8:
//  * agg kernels: mean degree 16 meant unroll-8 left a 0-7 edge SERIAL
//    remainder (full L2/LLC latency each) on most rows. Now every row is
//    processed in masked chunks of 8 (clamped index -> self row, fmaf mask),
//    so 8 gathers are always in flight. col[] read once per 64 edges with a
//    coalesced lane-parallel load + __shfl broadcast (halves mem-pipe instrs).
// norm factorization: out[n] = dinv[n]*(sum_{s->n} g[s] + g[n]) + b,
// where g = dinv[:,None] * (h @ W).
// ---------------------------------------------------------------------------

static inline size_t alignup(size_t x){ return (x + 511) & ~size_t(511); }

typedef float v4f __attribute__((ext_vector_type(4)));

#define NBUCK 1024          // histogram bins (dst>>7), NB=ceil(N/128) used
#define CHUNK 8192          // edges per block in hist/scatter
#define CCAP  3584          // max edges per bucket (mean ~2046, +30 sigma)

__global__ void zero_kernel(int* __restrict__ p, int n){
  int i = blockIdx.x*256 + threadIdx.x;
  if(i<n) p[i] = 0;
}

// Pass A: global histogram of dst>>7 (LDS-aggregated).
__global__ __launch_bounds__(256) void hist_kernel(const int* __restrict__ dst,
                                                   int* __restrict__ bcnt, int E){
  __shared__ int h[NBUCK];
  int t = threadIdx.x;
  for(int i=t;i<NBUCK;i+=256) h[i]=0;
  __syncthreads();
  int base = blockIdx.x*CHUNK;
  #pragma unroll 4
  for(int i=0;i<CHUNK;i+=256){
    int e = base+i+t;
    if(e<E) atomicAdd(&h[dst[e]>>7], 1);
  }
  __syncthreads();
  for(int i=t;i<NBUCK;i+=256) if(h[i]) atomicAdd(&bcnt[i], h[i]);
}

// Exclusive scan of 1024 bucket counts (single block). bbase = bfill = prefix.
__global__ void scan_buckets_kernel(const int* __restrict__ bcnt, int* __restrict__ bbase,
                                    int* __restrict__ bfill){
  __shared__ int sh[256];
  int t = threadIdx.x;
  int v0=bcnt[4*t], v1=bcnt[4*t+1], v2=bcnt[4*t+2], v3=bcnt[4*t+3];
  int ts = v0+v1+v2+v3;
  sh[t]=ts; __syncthreads();
  for(int off=1; off<256; off<<=1){
    int x=(t>=off)?sh[t-off]:0; __syncthreads();
    sh[t]+=x; __syncthreads();
  }
  int run = sh[t]-ts;
  int i0=4*t;
  bbase[i0+0]=run; bfill[i0+0]=run; run+=v0;
  bbase[i0+1]=run; bfill[i0+1]=run; run+=v1;
  bbase[i0+2]=run; bfill[i0+2]=run; run+=v2;
  bbase[i0+3]=run; bfill[i0+3]=run;
}

// Pass B: scatter packed (local_dst<<17 | src) into bucket regions.
__global__ __launch_bounds__(256) void scatter_kernel(const int* __restrict__ src,
                                                      const int* __restrict__ dst,
                                                      int* __restrict__ bfill,
                                                      int* __restrict__ pairs, int E){
  __shared__ int h[NBUCK];
  __shared__ int base[NBUCK];
  int t = threadIdx.x;
  for(int i=t;i<NBUCK;i+=256) h[i]=0;
  __syncthreads();
  int cbase = blockIdx.x*CHUNK;
  int d[CHUNK/256];
  #pragma unroll
  for(int i=0;i<CHUNK/256;i++){
    int e = cbase+i*256+t;
    d[i] = (e<E) ? dst[e] : -1;
    if(d[i]>=0) atomicAdd(&h[d[i]>>7], 1);
  }
  __syncthreads();
  for(int i=t;i<NBUCK;i+=256) base[i] = h[i] ? atomicAdd(&bfill[i], h[i]) : 0;
  __syncthreads();
  #pragma unroll
  for(int i=0;i<CHUNK/256;i++){
    int e = cbase+i*256+t;
    if(d[i]>=0){
      int b = d[i]>>7;
      int slot = atomicAdd(&base[b], 1);
      pairs[slot] = ((d[i]&127)<<17) | src[e];
    }
  }
}

// Pass C: one block per bucket (128 dst nodes). LDS counting sort ->
// row_ptr, dinv, and fully-sequential col writes.
__global__ __launch_bounds__(256) void bucket_csr_kernel(const int* __restrict__ pairs,
                                                         const int* __restrict__ bbase,
                                                         int* __restrict__ row_ptr,
                                                         float* __restrict__ dinv,
                                                         int* __restrict__ col,
                                                         int N, int E){
  __shared__ int hist[128];
  __shared__ int pref[128];
  __shared__ int fill[128];
  __shared__ int srcs[CCAP];
  int b = blockIdx.x, t = threadIdx.x;
  int s = bbase[b], e = bbase[b+1];
  int cnt = e - s; if(cnt > CCAP) cnt = CCAP;   // unreachable guard
  if(t<128) hist[t]=0;
  __syncthreads();
  int v[CCAP/256];
  #pragma unroll
  for(int i=0;i<CCAP/256;i++){
    int idx = i*256 + t;
    if(idx<cnt){ v[i]=pairs[s+idx]; atomicAdd(&hist[v[i]>>17], 1); }
  }
  __syncthreads();
  if(t<128) pref[t]=hist[t];
  __syncthreads();
  for(int off=1; off<128; off<<=1){
    int x=0;
    if(t<128 && t>=off) x=pref[t-off];
    __syncthreads();
    if(t<128) pref[t]+=x;
    __syncthreads();
  }
  if(t<128){
    int ex = pref[t]-hist[t];                 // exclusive prefix
    fill[t]=ex;
    int node = b*128 + t;
    if(node<N){
      row_ptr[node] = s + ex;
      dinv[node] = rsqrtf((float)(hist[t]+1)); // +1 self loop
    }
  }
  if(b==0 && t==0) row_ptr[N]=E;
  __syncthreads();
  #pragma unroll
  for(int i=0;i<CCAP/256;i++){
    int idx = i*256 + t;
    if(idx<cnt){
      int ld = v[i]>>17;
      int pos = atomicAdd(&fill[ld], 1);
      srcs[pos] = v[i] & 0x1FFFF;
    }
  }
  __syncthreads();
  for(int i=t;i<cnt;i+=256) col[s+i]=srcs[i];
}

// g[n,:] = dinv[n] * (h[n,:K] @ W[K,64]).
// LDS-staged: TR=32 rows staged with coalesced float4 loads; each of the
// 4 waves computes RW=8 rows; k-loop unroll capped at 2 (R7 spill lesson).
template<int K>
__global__ __launch_bounds__(256) void lin_kernel(const float* __restrict__ h,
                                                  const float* __restrict__ W,
                                                  const float* __restrict__ dinv,
                                                  float* __restrict__ g, int N){
  constexpr int TR = 32, RW = 8;
  __shared__ __align__(16) float hs[TR*K];
  int t = threadIdx.x, wave = t>>6, lane = t&63;
  long rbase = (long)blockIdx.x*TR;
  const v4f* hsrc = (const v4f*)(h + rbase*K);
  if(rbase + TR <= N){
    #pragma unroll
    for(int idx = t; idx < TR*K/4; idx += 256)
      ((v4f*)hs)[idx] = hsrc[idx];
  } else {
    int lim = (int)((N - rbase)*K/4);            // tail block
    for(int idx = t; idx < lim; idx += 256)
      ((v4f*)hs)[idx] = hsrc[idx];
  }
  __syncthreads();
  float acc[RW];
  #pragma unroll
  for(int r=0;r<RW;r++) acc[r]=0.f;
  const float* hw = hs + wave*RW*K;
  #pragma unroll 2
  for(int k=0;k<K;k+=4){
    float w0 = W[(k+0)*64+lane];
    float w1 = W[(k+1)*64+lane];
    float w2 = W[(k+2)*64+lane];
    float w3 = W[(k+3)*64+lane];
    #pragma unroll
    for(int r=0;r<RW;r++){
      v4f hv = *(const v4f*)&hw[r*K+k];
      acc[r] = fmaf(hv.w, w3, fmaf(hv.z, w2, fmaf(hv.y, w1, fmaf(hv.x, w0, acc[r]))));
    }
  }
  long row0 = rbase + wave*RW;
  #pragma unroll
  for(int r=0;r<RW;r++){
    if(row0 + r < N)
      g[(row0+r)*64 + lane] = dinv[row0+r]*acc[r];
  }
}

// Gather-sum body shared by agg / agg_final: returns
// acc = g[n,:] + sum_{CSR row n} g[col,:] for this lane's feature.
// Edges in masked chunks of 8 (clamp to self row n), col via one coalesced
// lane-parallel load per 64 edges + __shfl broadcast.
__device__ __forceinline__ float gather_row(const float* __restrict__ g,
                                            const int* __restrict__ col,
                                            int n, int s, int e, int lane){
  float acc = g[(size_t)n*64 + lane];          // self loop
  int i = s;
  while(i < e){
    int rem = e - i;
    int myc = (lane < rem) ? col[i + lane] : n;
    int cnt = rem < 64 ? rem : 64;
    for(int j=0; j<cnt; j+=8){
      int c0=__shfl(myc,j+0), c1=__shfl(myc,j+1), c2=__shfl(myc,j+2), c3=__shfl(myc,j+3);
      int c4=__shfl(myc,j+4), c5=__shfl(myc,j+5), c6=__shfl(myc,j+6), c7=__shfl(myc,j+7);
      float x0=g[(size_t)c0*64+lane], x1=g[(size_t)c1*64+lane];
      float x2=g[(size_t)c2*64+lane], x3=g[(size_t)c3*64+lane];
      float x4=g[(size_t)c4*64+lane], x5=g[(size_t)c5*64+lane];
      float x6=g[(size_t)c6*64+lane], x7=g[(size_t)c7*64+lane];
      float m1=(j+1<cnt)?1.f:0.f, m2=(j+2<cnt)?1.f:0.f, m3=(j+3<cnt)?1.f:0.f;
      float m4=(j+4<cnt)?1.f:0.f, m5=(j+5<cnt)?1.f:0.f, m6=(j+6<cnt)?1.f:0.f;
      float m7=(j+7<cnt)?1.f:0.f;
      acc += x0;                       // j+0 always valid
      acc = fmaf(m1, x1, acc); acc = fmaf(m2, x2, acc);
      acc = fmaf(m3, x3, acc); acc = fmaf(m4, x4, acc);
      acc = fmaf(m5, x5, acc); acc = fmaf(m6, x6, acc);
      acc = fmaf(m7, x7, acc);
    }
    i += 64;
  }
  return acc;
}

// h[n,:] = relu(dinv[n]*gather + bias).
__global__ __launch_bounds__(256) void agg_kernel(const float* __restrict__ g,
                                                  const int* __restrict__ row_ptr,
                                                  const int* __restrict__ col,
                                                  const float* __restrict__ dinv,
                                                  const float* __restrict__ bias,
                                                  float* __restrict__ h, int N){
  int wave = threadIdx.x>>6, lane = threadIdx.x&63;
  int n = blockIdx.x*4 + wave;
  if(n>=N) return;
  int s = row_ptr[n], e = row_ptr[n+1];
  float acc = gather_row(g, col, n, s, e, lane);
  float r = dinv[n]*acc + bias[lane];
  h[(size_t)n*64 + lane] = fmaxf(r, 0.0f);
}

// Layer-3 agg with fused FC + log_softmax epilogue: never materializes h3.
__global__ __launch_bounds__(256) void agg_final_kernel(const float* __restrict__ g,
                                                        const int* __restrict__ row_ptr,
                                                        const int* __restrict__ col,
                                                        const float* __restrict__ dinv,
                                                        const float* __restrict__ bias,
                                                        const float* __restrict__ Wfc,
                                                        const float* __restrict__ bfc,
                                                        float* __restrict__ out, int N){
  int wave = threadIdx.x>>6, lane = threadIdx.x&63;
  int n = blockIdx.x*4 + wave;
  if(n>=N) return;
  int s = row_ptr[n], e = row_ptr[n+1];
  float acc = gather_row(g, col, n, s, e, lane);
  float hv = fmaxf(dinv[n]*acc + bias[lane], 0.0f);   // h3[n][lane]
  float2 w = *(const float2*)&Wfc[lane*2];
  float p0 = hv*w.x, p1 = hv*w.y;
  for(int off=32; off; off>>=1){
    p0 += __shfl_down(p0, off);
    p1 += __shfl_down(p1, off);
  }
  if(lane==0){
    float l0 = p0 + bfc[0], l1 = p1 + bfc[1];
    float m  = fmaxf(l0, l1);
    float lse = m + logf(expf(l0-m) + expf(l1-m));
    out[(size_t)n*2+0] = l0 - lse;
    out[(size_t)n*2+1] = l1 - lse;
  }
}

extern "C" void kernel_launch(void* const* d_in, const int* in_sizes, int n_in,
                              void* d_out, int out_size, void* d_ws, size_t ws_size,
                              hipStream_t stream) {
  (void)n_in; (void)out_size; (void)ws_size;
  const float* x   = (const float*)d_in[0];
  const int*   ei  = (const int*)  d_in[1];
  const float* W1  = (const float*)d_in[2];
  const float* b1  = (const float*)d_in[3];
  const float* W2  = (const float*)d_in[4];
  const float* b2  = (const float*)d_in[5];
  const float* W3  = (const float*)d_in[6];
  const float* b3  = (const float*)d_in[7];
  const float* Wfc = (const float*)d_in[8];
  const float* bfc = (const float*)d_in[9];
  float* out = (float*)d_out;

  const int N = in_sizes[0] / 128;   // 100000
  const int E = in_sizes[1] / 2;     // 1600000
  const int* src = ei;
  const int* dst = ei + E;
  const int NB = (N + 127) / 128;    // 782 buckets

  // ---- workspace carve ----
  char* w = (char*)d_ws;
  int*   bcnt    = (int*)  w; w += alignup((size_t)NBUCK*4);
  int*   bbase   = (int*)  w; w += alignup((size_t)(NBUCK+1)*4);
  int*   bfill   = (int*)  w; w += alignup((size_t)NBUCK*4);
  int*   pairs   = (int*)  w; w += alignup((size_t)E*4);
  int*   row_ptr = (int*)  w; w += alignup((size_t)(N+1)*4);
  float* dinv    = (float*)w; w += alignup((size_t)N*4);
  int*   col     = (int*)  w; w += alignup((size_t)E*4);
  float* bufA    = (float*)w; w += alignup((size_t)N*64*4);
  float* bufB    = (float*)w; w += alignup((size_t)N*64*4);

  const int nblkE   = (E + CHUNK - 1) / CHUNK;   // 196
  const int nblkLin = (N + 31) / 32;             // TR=32 -> 3125 (exact)
  const int nblkAgg = (N + 3) / 4;

  // ---- CSR build ----
  zero_kernel<<<(NBUCK+255)/256, 256, 0, stream>>>(bcnt, NBUCK);
  hist_kernel<<<nblkE, 256, 0, stream>>>(dst, bcnt, E);
  scan_buckets_kernel<<<1, 256, 0, stream>>>(bcnt, bbase, bfill);
  scatter_kernel<<<nblkE, 256, 0, stream>>>(src, dst, bfill, pairs, E);
  bucket_csr_kernel<<<NB, 256, 0, stream>>>(pairs, bbase, row_ptr, dinv, col, N, E);

  // ---- layer 1: x[N,128] ----
  lin_kernel<128><<<nblkLin, 256, 0, stream>>>(x, W1, dinv, bufA, N);
  agg_kernel<<<nblkAgg, 256, 0, stream>>>(bufA, row_ptr, col, dinv, b1, bufB, N);
  // ---- layer 2 ----
  lin_kernel<64><<<nblkLin, 256, 0, stream>>>(bufB, W2, dinv, bufA, N);
  agg_kernel<<<nblkAgg, 256, 0, stream>>>(bufA, row_ptr, col, dinv, b2, bufB, N);
  // ---- layer 3 + FC + log_softmax (fused) ----
  lin_kernel<64><<<nblkLin, 256, 0, stream>>>(bufB, W3, dinv, bufA, N);
  agg_final_kernel<<<nblkAgg, 256, 0, stream>>>(bufA, row_ptr, col, dinv, b3,
                                                Wfc, bfc, out, N);
}